// Round 10
// baseline (315.011 us; speedup 1.0000x reference)
//
#include <hip/hip_runtime.h>
#include <hip/hip_bf16.h>
#include <math.h>

#define N_NODES 50000
#define N_EDGES 800000
#define NEG_SLOPE 0.2f
#define NBUCK ((N_NODES + 255) / 256)   // 196 buckets of 256 dsts
#define CCHUNK 4096
#define DCAP 8192

__device__ inline float lrelu(float x) { return fmaxf(x, NEG_SLOPE * x); }

__device__ inline unsigned bf16rne(float f) {
    unsigned u = __float_as_uint(f);
    return (u + 0x7fffu + ((u >> 16) & 1u)) >> 16;
}

// ---------------- CSR build: LDS-staged bucket sort ----------------
__global__ void zerobuf_kernel(int* __restrict__ p) {
    int i = threadIdx.x;
    if (i < NBUCK) p[i] = 0;
}

__global__ __launch_bounds__(256) void bucketcount_kernel(const int* __restrict__ ei,
                                                          int* __restrict__ gbcnt) {
    __shared__ int lc[NBUCK];
    for (int i = threadIdx.x; i < NBUCK; i += 256) lc[i] = 0;
    __syncthreads();
    int stride = gridDim.x * 256;
    for (int e = blockIdx.x * 256 + threadIdx.x; e < N_EDGES; e += stride)
        atomicAdd(&lc[ei[N_EDGES + e] >> 8], 1);
    __syncthreads();
    for (int i = threadIdx.x; i < NBUCK; i += 256)
        if (lc[i]) atomicAdd(&gbcnt[i], lc[i]);
}

__global__ __launch_bounds__(256) void bucketscan_kernel(const int* __restrict__ gbcnt,
                                                         int* __restrict__ bbase,
                                                         int* __restrict__ bcur) {
    __shared__ int ss[256];
    int t = threadIdx.x;
    int v = (t < NBUCK) ? gbcnt[t] : 0;
    ss[t] = v;
    __syncthreads();
    for (int d = 1; d < 256; d <<= 1) {
        int u = (t >= d) ? ss[t - d] : 0;
        __syncthreads();
        ss[t] += u;
        __syncthreads();
    }
    int excl = ss[t] - v;
    if (t < NBUCK) { bbase[t] = excl; bcur[t] = excl; }
    if (t == 0) bbase[NBUCK] = N_EDGES;
}

__global__ __launch_bounds__(256) void bucketscatter_kernel(const int* __restrict__ ei,
                                                            int* __restrict__ bcur,
                                                            int2* __restrict__ bpairs) {
    __shared__ int cnt[NBUCK], startl[NBUCK], baseg[NBUCK], cur2[NBUCK];
    __shared__ int ss[256];
    __shared__ int2 stage[CCHUNK];
    int t = threadIdx.x;
    int e0 = blockIdx.x * CCHUNK;
    int nume = min(CCHUNK, N_EDGES - e0);
    for (int i = t; i < NBUCK; i += 256) { cnt[i] = 0; cur2[i] = 0; }
    __syncthreads();
    int src[CCHUNK / 256], dst[CCHUNK / 256];
    #pragma unroll
    for (int j = 0; j < CCHUNK / 256; ++j) {
        int idx = t + j * 256;
        if (idx < nume) {
            src[j] = ei[e0 + idx];
            dst[j] = ei[N_EDGES + e0 + idx];
            atomicAdd(&cnt[dst[j] >> 8], 1);
        } else dst[j] = -1;
    }
    __syncthreads();
    {
        int v = (t < NBUCK) ? cnt[t] : 0;
        ss[t] = v;
        __syncthreads();
        for (int d = 1; d < 256; d <<= 1) {
            int u = (t >= d) ? ss[t - d] : 0;
            __syncthreads();
            ss[t] += u;
            __syncthreads();
        }
        if (t < NBUCK) startl[t] = ss[t] - v;
    }
    __syncthreads();
    if (t < NBUCK && cnt[t] > 0) baseg[t] = atomicAdd(&bcur[t], cnt[t]);
    __syncthreads();
    #pragma unroll
    for (int j = 0; j < CCHUNK / 256; ++j) {
        if (dst[j] >= 0) {
            int b = dst[j] >> 8;
            int slot = startl[b] + atomicAdd(&cur2[b], 1);
            stage[slot] = make_int2(src[j], dst[j]);
        }
    }
    __syncthreads();
    for (int i = t; i < nume; i += 256) {
        int2 p = stage[i];
        int b = p.y >> 8;
        bpairs[baseg[b] + (i - startl[b])] = p;
    }
}

__global__ __launch_bounds__(256) void csrfinalize_kernel(const int2* __restrict__ bpairs,
                                                          const int* __restrict__ bbase,
                                                          int* __restrict__ ptr,
                                                          int* __restrict__ csr) {
    __shared__ int cnt[256], excl[256], cur[256];
    __shared__ int ss[256];
    __shared__ int2 P[DCAP];
    int b = blockIdx.x, t = threadIdx.x;
    int bb = bbase[b], be = bbase[b + 1];
    int n = be - bb;
    int d0 = b << 8;
    int dmax = min(256, N_NODES - d0);
    bool fits = (n <= DCAP);
    cnt[t] = 0; cur[t] = 0;
    __syncthreads();
    for (int i = t; i < n; i += 256) {
        int2 p = bpairs[bb + i];
        if (fits) P[i] = p;
        atomicAdd(&cnt[p.y & 255], 1);
    }
    __syncthreads();
    {
        int v = cnt[t];
        ss[t] = v;
        __syncthreads();
        for (int d = 1; d < 256; d <<= 1) {
            int u = (t >= d) ? ss[t - d] : 0;
            __syncthreads();
            ss[t] += u;
            __syncthreads();
        }
        excl[t] = ss[t] - v;
    }
    __syncthreads();
    if (t < dmax) ptr[d0 + t] = bb + excl[t];
    if (b == NBUCK - 1 && t == 0) ptr[N_NODES] = N_EDGES;
    for (int i = t; i < n; i += 256) {
        int2 p = fits ? P[i] : bpairs[bb + i];
        int ld = p.y & 255;
        int pos = bb + excl[ld] + atomicAdd(&cur[ld], 1);
        csr[pos] = p.x;
    }
}

// ---- GEMM + fused attention-logit epilogue; software-pipelined W loads ----
#define GB_ROWS 32
template <int H>
__global__ __launch_bounds__(256) void gemm_kernel(const float* __restrict__ X,
                                                   const float* __restrict__ W,
                                                   const float* __restrict__ asrc,
                                                   const float* __restrict__ adst,
                                                   unsigned short* __restrict__ Hb,
                                                   float* __restrict__ als,
                                                   float* __restrict__ ald,
                                                   int nrows) {
    __shared__ float xt[GB_ROWS][132];
    const int tid = threadIdx.x;
    const int r0 = blockIdx.x * GB_ROWS;
    #pragma unroll
    for (int i = 0; i < 4; ++i) {
        int idx = tid + 256 * i;          // 0..1023 float4 slots
        int r = idx >> 5, c4 = (idx & 31) * 4;
        int gr = r0 + r;
        float4 v = make_float4(0.f, 0.f, 0.f, 0.f);
        if (gr < nrows) v = *(const float4*)(X + (size_t)gr * 128 + c4);
        *(float4*)(&xt[r][c4]) = v;
    }
    __syncthreads();
    const int c0 = (tid & 31) * 4;
    const int rbase = (tid >> 5) * 4;
    const int q = tid & 31;
    const float4* Wv = (const float4*)(W + c0);   // Wv[k*32] = W[k*128+c0..c0+3]
    float acc[4][4];
    #pragma unroll
    for (int i = 0; i < 4; ++i)
        #pragma unroll
        for (int j = 0; j < 4; ++j) acc[i][j] = 0.f;

    float4 wa[4], wb[4];
    #pragma unroll
    for (int i = 0; i < 4; ++i) wa[i] = Wv[(size_t)i * 32];          // k=0..3
    for (int k8 = 0; k8 < 128; k8 += 8) {
        #pragma unroll
        for (int i = 0; i < 4; ++i) wb[i] = Wv[(size_t)(k8 + 4 + i) * 32];   // k8+4..k8+7
        #pragma unroll
        for (int kk = 0; kk < 4; ++kk) {
            int k = k8 + kk;
            float4 w4 = wa[kk];
            #pragma unroll
            for (int i = 0; i < 4; ++i) {
                float xv = xt[rbase + i][k];
                acc[i][0] = fmaf(xv, w4.x, acc[i][0]);
                acc[i][1] = fmaf(xv, w4.y, acc[i][1]);
                acc[i][2] = fmaf(xv, w4.z, acc[i][2]);
                acc[i][3] = fmaf(xv, w4.w, acc[i][3]);
            }
        }
        #pragma unroll
        for (int i = 0; i < 4; ++i) {
            int kp = min(k8 + 8 + i, 127);                           // clamp; unused on last iter
            wa[i] = Wv[(size_t)kp * 32];
        }
        #pragma unroll
        for (int kk = 0; kk < 4; ++kk) {
            int k = k8 + 4 + kk;
            float4 w4 = wb[kk];
            #pragma unroll
            for (int i = 0; i < 4; ++i) {
                float xv = xt[rbase + i][k];
                acc[i][0] = fmaf(xv, w4.x, acc[i][0]);
                acc[i][1] = fmaf(xv, w4.y, acc[i][1]);
                acc[i][2] = fmaf(xv, w4.z, acc[i][2]);
                acc[i][3] = fmaf(xv, w4.w, acc[i][3]);
            }
        }
    }

    float4 as4 = *(const float4*)(asrc + c0);
    float4 ad4 = *(const float4*)(adst + c0);
    #pragma unroll
    for (int i = 0; i < 4; ++i) {
        int gr = r0 + rbase + i;
        bool ok = gr < nrows;
        if (ok) {
            uint2 p;
            p.x = bf16rne(acc[i][0]) | (bf16rne(acc[i][1]) << 16);
            p.y = bf16rne(acc[i][2]) | (bf16rne(acc[i][3]) << 16);
            *(uint2*)(Hb + (size_t)gr * 128 + c0) = p;
        }
        float sp = acc[i][0] * as4.x + acc[i][1] * as4.y + acc[i][2] * as4.z + acc[i][3] * as4.w;
        float dp = acc[i][0] * ad4.x + acc[i][1] * ad4.y + acc[i][2] * ad4.z + acc[i][3] * ad4.w;
        #pragma unroll
        for (int off = 1; off < (H == 2 ? 16 : 32); off <<= 1) {
            sp += __shfl_xor(sp, off);
            dp += __shfl_xor(dp, off);
        }
        if (ok) {
            if (H == 2) {
                if (q == 0)  { als[(size_t)gr * 2]     = sp; ald[(size_t)gr * 2]     = dp; }
                if (q == 16) { als[(size_t)gr * 2 + 1] = sp; ald[(size_t)gr * 2 + 1] = dp; }
            } else {
                if (q == 0) { als[gr] = sp; ald[gr] = dp; }
            }
        }
    }
}

// ---- fused softmax+gather: lane-parallel softmax, LDS-broadcast gather (R8) ----
template <int H, int DO_ELU>
__global__ __launch_bounds__(256) void aggregate_kernel(const unsigned short* __restrict__ Hb,
                                                        const float* __restrict__ als,
                                                        const float* __restrict__ aldv,
                                                        const int* __restrict__ ptr,
                                                        const int* __restrict__ csr,
                                                        const float* __restrict__ bias,
                                                        float* __restrict__ out) {
    __shared__ int   s_src[4][64];
    __shared__ float s_p[4][H][64];
    const int w = threadIdx.x >> 6;
    const int lane = threadIdx.x & 63;
    const int d = blockIdx.x * 4 + w;
    if (d >= N_NODES) return;
    const int head = (H == 2) ? (lane >> 5) : 0;

    int beg = ptr[d], end = ptr[d + 1];

    float ald0, ald1 = 0.f, es0, es1 = 0.f;
    if (H == 2) {
        float2 ta = *(const float2*)(aldv + (size_t)d * 2);
        float2 ts = *(const float2*)(als + (size_t)d * 2);
        ald0 = ta.x; ald1 = ta.y;
        es0 = lrelu(ts.x + ald0); es1 = lrelu(ts.y + ald1);
    } else {
        ald0 = aldv[d]; es0 = lrelu(als[d] + ald0);
    }

    int k0 = beg + lane;
    int src0 = 0;
    float e0 = -INFINITY, e1 = -INFINITY;
    if (k0 < end) {
        src0 = csr[k0];
        if (H == 2) {
            float2 t = *(const float2*)(als + (size_t)src0 * 2);
            e0 = lrelu(t.x + ald0); e1 = lrelu(t.y + ald1);
        } else e0 = lrelu(als[src0] + ald0);
    }
    float m0 = fmaxf(es0, e0);
    float m1 = (H == 2) ? fmaxf(es1, e1) : 0.f;
    for (int k = k0 + 64; k < end; k += 64) {
        int s = csr[k];
        if (H == 2) {
            float2 t = *(const float2*)(als + (size_t)s * 2);
            m0 = fmaxf(m0, lrelu(t.x + ald0));
            m1 = fmaxf(m1, lrelu(t.y + ald1));
        } else m0 = fmaxf(m0, lrelu(als[s] + ald0));
    }
    #pragma unroll
    for (int off = 32; off; off >>= 1) {
        m0 = fmaxf(m0, __shfl_xor(m0, off));
        if (H == 2) m1 = fmaxf(m1, __shfl_xor(m1, off));
    }

    float l0 = 0.f, l1 = 0.f;
    float ax0 = 0.f, ay0 = 0.f, ax1 = 0.f, ay1 = 0.f;
    float ax2 = 0.f, ay2 = 0.f, ax3 = 0.f, ay3 = 0.f;

    for (int t0 = beg; t0 < end; t0 += 64) {
        int cnt = min(64, end - t0);
        int k = t0 + lane;
        if (k < end) {
            int s; float f0, f1 = 0.f;
            if (t0 == beg) { s = src0; f0 = e0; f1 = e1; }
            else {
                s = csr[k];
                if (H == 2) {
                    float2 t = *(const float2*)(als + (size_t)s * 2);
                    f0 = lrelu(t.x + ald0); f1 = lrelu(t.y + ald1);
                } else f0 = lrelu(als[s] + ald0);
            }
            float p0 = __expf(f0 - m0);
            l0 += p0;
            s_src[w][lane] = s;
            s_p[w][0][lane] = p0;
            if (H == 2) {
                float p1 = __expf(f1 - m1);
                l1 += p1;
                s_p[w][1][lane] = p1;
            }
        }
        int j = 0;
        for (; j + 3 < cnt; j += 4) {
            int sA = s_src[w][j],     sB = s_src[w][j + 1];
            int sC = s_src[w][j + 2], sD = s_src[w][j + 3];
            float pA = s_p[w][head][j],     pB = s_p[w][head][j + 1];
            float pC = s_p[w][head][j + 2], pD = s_p[w][head][j + 3];
            unsigned uA = ((const unsigned*)(Hb + (size_t)sA * 128))[lane];
            unsigned uB = ((const unsigned*)(Hb + (size_t)sB * 128))[lane];
            unsigned uC = ((const unsigned*)(Hb + (size_t)sC * 128))[lane];
            unsigned uD = ((const unsigned*)(Hb + (size_t)sD * 128))[lane];
            ax0 = fmaf(pA, __uint_as_float(uA << 16), ax0);
            ay0 = fmaf(pA, __uint_as_float(uA & 0xffff0000u), ay0);
            ax1 = fmaf(pB, __uint_as_float(uB << 16), ax1);
            ay1 = fmaf(pB, __uint_as_float(uB & 0xffff0000u), ay1);
            ax2 = fmaf(pC, __uint_as_float(uC << 16), ax2);
            ay2 = fmaf(pC, __uint_as_float(uC & 0xffff0000u), ay2);
            ax3 = fmaf(pD, __uint_as_float(uD << 16), ax3);
            ay3 = fmaf(pD, __uint_as_float(uD & 0xffff0000u), ay3);
        }
        for (; j < cnt; ++j) {
            int sA = s_src[w][j];
            float pA = s_p[w][head][j];
            unsigned uA = ((const unsigned*)(Hb + (size_t)sA * 128))[lane];
            ax0 = fmaf(pA, __uint_as_float(uA << 16), ax0);
            ay0 = fmaf(pA, __uint_as_float(uA & 0xffff0000u), ay0);
        }
    }

    float ax = (ax0 + ax1) + (ax2 + ax3);
    float ay = (ay0 + ay1) + (ay2 + ay3);
    float mh  = (head == 0) ? m0 : m1;
    float esh = (head == 0) ? es0 : es1;
    float psh = __expf(esh - mh);
    {
        unsigned u = ((const unsigned*)(Hb + (size_t)d * 128))[lane];
        ax = fmaf(psh, __uint_as_float(u << 16), ax);
        ay = fmaf(psh, __uint_as_float(u & 0xffff0000u), ay);
    }
    #pragma unroll
    for (int off = 32; off; off >>= 1) {
        l0 += __shfl_xor(l0, off);
        if (H == 2) l1 += __shfl_xor(l1, off);
    }
    float denom = ((head == 0) ? l0 : l1) + psh;
    float inv = 1.f / (denom + 1e-16f);
    float o0 = ax * inv + bias[2 * lane];
    float o1 = ay * inv + bias[2 * lane + 1];
    if (DO_ELU) {
        o0 = o0 > 0.f ? o0 : expm1f(o0);
        o1 = o1 > 0.f ? o1 : expm1f(o1);
    }
    ((float2*)(out + (size_t)d * 128))[lane] = make_float2(o0, o1);
}

// ---------------- launch ----------------
extern "C" void kernel_launch(void* const* d_in, const int* in_sizes, int n_in,
                              void* d_out, int out_size, void* d_ws, size_t ws_size,
                              hipStream_t stream) {
    const float* x      = (const float*)d_in[0];
    const int*   ei     = (const int*)d_in[1];
    const float* W1     = (const float*)d_in[2];
    const float* a_src1 = (const float*)d_in[3];
    const float* a_dst1 = (const float*)d_in[4];
    const float* b1     = (const float*)d_in[5];
    const float* W2     = (const float*)d_in[6];
    const float* a_src2 = (const float*)d_in[7];
    const float* a_dst2 = (const float*)d_in[8];
    const float* b2     = (const float*)d_in[9];
    float* out = (float*)d_out;

    char* ws = (char*)d_ws;
    size_t off = 0;
    auto alloc = [&](size_t bytes) { void* p = ws + off; off += (bytes + 255) & ~(size_t)255; return p; };
    int*   ptr    = (int*)alloc((N_NODES + 1) * sizeof(int));
    int*   gbcnt  = (int*)alloc(NBUCK * sizeof(int));
    int*   bbase  = (int*)alloc((NBUCK + 1) * sizeof(int));
    int*   bcur   = (int*)alloc(NBUCK * sizeof(int));
    int2*  bpairs = (int2*)alloc((size_t)N_EDGES * sizeof(int2));
    int*   csr    = (int*)alloc(N_EDGES * sizeof(int));
    float* x2     = (float*)alloc((size_t)N_NODES * 128 * sizeof(float));
    unsigned short* hb = (unsigned short*)alloc((size_t)N_NODES * 128 * sizeof(unsigned short));
    float* als    = (float*)alloc(N_NODES * 2 * sizeof(float));
    float* ald    = (float*)alloc(N_NODES * 2 * sizeof(float));

    // ---- CSR build (bucket sort; same graph both layers) ----
    zerobuf_kernel<<<1, 256, 0, stream>>>(gbcnt);
    bucketcount_kernel<<<256, 256, 0, stream>>>(ei, gbcnt);
    bucketscan_kernel<<<1, 256, 0, stream>>>(gbcnt, bbase, bcur);
    bucketscatter_kernel<<<(N_EDGES + CCHUNK - 1) / CCHUNK, 256, 0, stream>>>(ei, bcur, bpairs);
    csrfinalize_kernel<<<NBUCK, 256, 0, stream>>>(bpairs, bbase, ptr, csr);

    int gblocks = (N_NODES + GB_ROWS - 1) / GB_ROWS;
    int wblocks = (N_NODES + 3) / 4;

    // ---- layer 1 ----
    gemm_kernel<2><<<gblocks, 256, 0, stream>>>(x, W1, a_src1, a_dst1, hb, als, ald, N_NODES);
    aggregate_kernel<2, 1><<<wblocks, 256, 0, stream>>>(hb, als, ald, ptr, csr, b1, x2);

    // ---- layer 2 ----
    gemm_kernel<1><<<gblocks, 256, 0, stream>>>(x2, W2, a_src2, a_dst2, hb, als, ald, N_NODES);
    aggregate_kernel<1, 0><<<wblocks, 256, 0, stream>>>(hb, als, ald, ptr, csr, b2, out);
}

// Round 11
// 185.275 us; speedup vs baseline: 1.7002x; 1.7002x over previous
//
#include <hip/hip_runtime.h>
#include <hip/hip_bf16.h>
#include <math.h>

#define N_NODES 50000
#define NPAD 50048                      // 391 * 128
#define N_EDGES 800000
#define NEG_SLOPE 0.2f
#define NBUCK ((N_NODES + 255) / 256)   // 196 buckets of 256 dsts
#define CCHUNK 4096
#define DCAP 8192

__device__ inline float lrelu(float x) { return fmaxf(x, NEG_SLOPE * x); }

__device__ inline unsigned bf16rne(float f) {
    unsigned u = __float_as_uint(f);
    return (u + 0x7fffu + ((u >> 16) & 1u)) >> 16;
}
__device__ inline float bf2f(unsigned h) { return __uint_as_float(h << 16); }

// ---------------- CSR build: LDS-staged bucket sort ----------------
__global__ void zerobuf_kernel(int* __restrict__ p) {
    int i = threadIdx.x;
    if (i < NBUCK) p[i] = 0;
}

__global__ __launch_bounds__(256) void bucketcount_kernel(const int* __restrict__ ei,
                                                          int* __restrict__ gbcnt) {
    __shared__ int lc[NBUCK];
    for (int i = threadIdx.x; i < NBUCK; i += 256) lc[i] = 0;
    __syncthreads();
    int stride = gridDim.x * 256;
    for (int e = blockIdx.x * 256 + threadIdx.x; e < N_EDGES; e += stride)
        atomicAdd(&lc[ei[N_EDGES + e] >> 8], 1);
    __syncthreads();
    for (int i = threadIdx.x; i < NBUCK; i += 256)
        if (lc[i]) atomicAdd(&gbcnt[i], lc[i]);
}

__global__ __launch_bounds__(256) void bucketscan_kernel(const int* __restrict__ gbcnt,
                                                         int* __restrict__ bbase,
                                                         int* __restrict__ bcur) {
    __shared__ int ss[256];
    int t = threadIdx.x;
    int v = (t < NBUCK) ? gbcnt[t] : 0;
    ss[t] = v;
    __syncthreads();
    for (int d = 1; d < 256; d <<= 1) {
        int u = (t >= d) ? ss[t - d] : 0;
        __syncthreads();
        ss[t] += u;
        __syncthreads();
    }
    int excl = ss[t] - v;
    if (t < NBUCK) { bbase[t] = excl; bcur[t] = excl; }
    if (t == 0) bbase[NBUCK] = N_EDGES;
}

__global__ __launch_bounds__(256) void bucketscatter_kernel(const int* __restrict__ ei,
                                                            int* __restrict__ bcur,
                                                            int2* __restrict__ bpairs) {
    __shared__ int cnt[NBUCK], startl[NBUCK], baseg[NBUCK], cur2[NBUCK];
    __shared__ int ss[256];
    __shared__ int2 stage[CCHUNK];
    int t = threadIdx.x;
    int e0 = blockIdx.x * CCHUNK;
    int nume = min(CCHUNK, N_EDGES - e0);
    for (int i = t; i < NBUCK; i += 256) { cnt[i] = 0; cur2[i] = 0; }
    __syncthreads();
    int src[CCHUNK / 256], dst[CCHUNK / 256];
    #pragma unroll
    for (int j = 0; j < CCHUNK / 256; ++j) {
        int idx = t + j * 256;
        if (idx < nume) {
            src[j] = ei[e0 + idx];
            dst[j] = ei[N_EDGES + e0 + idx];
            atomicAdd(&cnt[dst[j] >> 8], 1);
        } else dst[j] = -1;
    }
    __syncthreads();
    {
        int v = (t < NBUCK) ? cnt[t] : 0;
        ss[t] = v;
        __syncthreads();
        for (int d = 1; d < 256; d <<= 1) {
            int u = (t >= d) ? ss[t - d] : 0;
            __syncthreads();
            ss[t] += u;
            __syncthreads();
        }
        if (t < NBUCK) startl[t] = ss[t] - v;
    }
    __syncthreads();
    if (t < NBUCK && cnt[t] > 0) baseg[t] = atomicAdd(&bcur[t], cnt[t]);
    __syncthreads();
    #pragma unroll
    for (int j = 0; j < CCHUNK / 256; ++j) {
        if (dst[j] >= 0) {
            int b = dst[j] >> 8;
            int slot = startl[b] + atomicAdd(&cur2[b], 1);
            stage[slot] = make_int2(src[j], dst[j]);
        }
    }
    __syncthreads();
    for (int i = t; i < nume; i += 256) {
        int2 p = stage[i];
        int b = p.y >> 8;
        bpairs[baseg[b] + (i - startl[b])] = p;
    }
}

__global__ __launch_bounds__(256) void csrfinalize_kernel(const int2* __restrict__ bpairs,
                                                          const int* __restrict__ bbase,
                                                          int* __restrict__ ptr,
                                                          int* __restrict__ csr) {
    __shared__ int cnt[256], excl[256], cur[256];
    __shared__ int ss[256];
    __shared__ int2 P[DCAP];
    int b = blockIdx.x, t = threadIdx.x;
    int bb = bbase[b], be = bbase[b + 1];
    int n = be - bb;
    int d0 = b << 8;
    int dmax = min(256, N_NODES - d0);
    bool fits = (n <= DCAP);
    cnt[t] = 0; cur[t] = 0;
    __syncthreads();
    for (int i = t; i < n; i += 256) {
        int2 p = bpairs[bb + i];
        if (fits) P[i] = p;
        atomicAdd(&cnt[p.y & 255], 1);
    }
    __syncthreads();
    {
        int v = cnt[t];
        ss[t] = v;
        __syncthreads();
        for (int d = 1; d < 256; d <<= 1) {
            int u = (t >= d) ? ss[t - d] : 0;
            __syncthreads();
            ss[t] += u;
            __syncthreads();
        }
        excl[t] = ss[t] - v;
    }
    __syncthreads();
    if (t < dmax) ptr[d0 + t] = bb + excl[t];
    if (b == NBUCK - 1 && t == 0) ptr[N_NODES] = N_EDGES;
    for (int i = t; i < n; i += 256) {
        int2 p = fits ? P[i] : bpairs[bb + i];
        int ld = p.y & 255;
        int pos = bb + excl[ld] + atomicAdd(&cur[ld], 1);
        csr[pos] = p.x;
    }
}

// ---------------- prep: bf16-split conversions ----------------
// x -> (xh, xl); also zero-fills pad rows of x2h/x2l (never written by aggregate)
__global__ __launch_bounds__(256) void convx_kernel(const float* __restrict__ x,
                                                    unsigned short* __restrict__ xh,
                                                    unsigned short* __restrict__ xl,
                                                    unsigned short* __restrict__ x2h,
                                                    unsigned short* __restrict__ x2l) {
    int q = blockIdx.x * 256 + threadIdx.x;       // quad index
    if (q >= NPAD * 128 / 4) return;
    int e = q * 4;
    int row = e >> 7;
    float vv[4] = {0.f, 0.f, 0.f, 0.f};
    if (row < N_NODES) {
        float4 v = *(const float4*)(x + e);
        vv[0] = v.x; vv[1] = v.y; vv[2] = v.z; vv[3] = v.w;
    }
    ushort4 hh, ll;
    unsigned h0 = bf16rne(vv[0]), h1 = bf16rne(vv[1]), h2 = bf16rne(vv[2]), h3 = bf16rne(vv[3]);
    hh.x = h0; hh.y = h1; hh.z = h2; hh.w = h3;
    ll.x = bf16rne(vv[0] - bf2f(h0));
    ll.y = bf16rne(vv[1] - bf2f(h1));
    ll.z = bf16rne(vv[2] - bf2f(h2));
    ll.w = bf16rne(vv[3] - bf2f(h3));
    *(ushort4*)(xh + e) = hh;
    *(ushort4*)(xl + e) = ll;
    if (row >= N_NODES) {
        ushort4 z = {0, 0, 0, 0};
        *(ushort4*)(x2h + e) = z;
        *(ushort4*)(x2l + e) = z;
    }
}

// W[k][c] -> Wt[c][k] split (128x128)
__global__ __launch_bounds__(256) void convw_kernel(const float* __restrict__ W,
                                                    unsigned short* __restrict__ wth,
                                                    unsigned short* __restrict__ wtl) {
    int idx = blockIdx.x * 256 + threadIdx.x;     // = c*128 + k
    if (idx >= 128 * 128) return;
    int c = idx >> 7, k = idx & 127;
    float v = W[(size_t)k * 128 + c];
    unsigned h = bf16rne(v);
    wth[idx] = (unsigned short)h;
    wtl[idx] = (unsigned short)bf16rne(v - bf2f(h));
}

// ---- MFMA GEMM (bf16x2 split, ~f32 accurate) + attention-logit epilogue ----
// Per wave: 32 rows x 128 cols. A from global [row][k] bf16; B from L1-hot Wt [c][k].
template <int H>
__global__ __launch_bounds__(256) void gemm_mfma_kernel(const unsigned short* __restrict__ Ah,
                                                        const unsigned short* __restrict__ Al,
                                                        const unsigned short* __restrict__ Bh,
                                                        const unsigned short* __restrict__ Bl,
                                                        const float* __restrict__ asrc,
                                                        const float* __restrict__ adst,
                                                        unsigned short* __restrict__ Hb,
                                                        float* __restrict__ als,
                                                        float* __restrict__ ald,
                                                        int nrows) {
    using bf16x8 = __attribute__((ext_vector_type(8))) short;
    using f32x4  = __attribute__((ext_vector_type(4))) float;
    const int lane = threadIdx.x & 63;
    const int wv = threadIdx.x >> 6;
    const int l15 = lane & 15;
    const int g = lane >> 4;
    const int lk = g * 8;
    const int rowbase = blockIdx.x * 128 + wv * 32;

    f32x4 acc[2][8];
    #pragma unroll
    for (int rt = 0; rt < 2; ++rt)
        #pragma unroll
        for (int ct = 0; ct < 8; ++ct) acc[rt][ct] = (f32x4){0.f, 0.f, 0.f, 0.f};

    #pragma unroll
    for (int kc = 0; kc < 4; ++kc) {
        const int ko = kc * 32 + lk;
        bf16x8 ah0 = *(const bf16x8*)(Ah + (size_t)(rowbase + l15) * 128 + ko);
        bf16x8 ah1 = *(const bf16x8*)(Ah + (size_t)(rowbase + 16 + l15) * 128 + ko);
        bf16x8 al0 = *(const bf16x8*)(Al + (size_t)(rowbase + l15) * 128 + ko);
        bf16x8 al1 = *(const bf16x8*)(Al + (size_t)(rowbase + 16 + l15) * 128 + ko);
        #pragma unroll
        for (int ct = 0; ct < 8; ++ct) {
            bf16x8 bh = *(const bf16x8*)(Bh + (size_t)(ct * 16 + l15) * 128 + ko);
            bf16x8 bl = *(const bf16x8*)(Bl + (size_t)(ct * 16 + l15) * 128 + ko);
            acc[0][ct] = __builtin_amdgcn_mfma_f32_16x16x32_bf16(ah0, bh, acc[0][ct], 0, 0, 0);
            acc[0][ct] = __builtin_amdgcn_mfma_f32_16x16x32_bf16(ah0, bl, acc[0][ct], 0, 0, 0);
            acc[0][ct] = __builtin_amdgcn_mfma_f32_16x16x32_bf16(al0, bh, acc[0][ct], 0, 0, 0);
            acc[1][ct] = __builtin_amdgcn_mfma_f32_16x16x32_bf16(ah1, bh, acc[1][ct], 0, 0, 0);
            acc[1][ct] = __builtin_amdgcn_mfma_f32_16x16x32_bf16(ah1, bl, acc[1][ct], 0, 0, 0);
            acc[1][ct] = __builtin_amdgcn_mfma_f32_16x16x32_bf16(al1, bh, acc[1][ct], 0, 0, 0);
        }
    }

    // epilogue: C/D layout col = lane&15, row = (lane>>4)*4 + j  [verified m89/m91]
    float as8[8], ad8[8];
    #pragma unroll
    for (int ct = 0; ct < 8; ++ct) { as8[ct] = asrc[ct * 16 + l15]; ad8[ct] = adst[ct * 16 + l15]; }

    #pragma unroll
    for (int rt = 0; rt < 2; ++rt) {
        #pragma unroll
        for (int ct = 0; ct < 8; ++ct) {
            #pragma unroll
            for (int j = 0; j < 4; ++j) {
                int row = rowbase + rt * 16 + g * 4 + j;
                if (row < nrows)
                    Hb[(size_t)row * 128 + ct * 16 + l15] = (unsigned short)bf16rne(acc[rt][ct][j]);
            }
        }
        #pragma unroll
        for (int j = 0; j < 4; ++j) {
            int row = rowbase + rt * 16 + g * 4 + j;
            if (H == 2) {
                float sp0 = 0.f, sp1 = 0.f, dp0 = 0.f, dp1 = 0.f;
                #pragma unroll
                for (int ct = 0; ct < 4; ++ct) { sp0 += acc[rt][ct][j] * as8[ct]; dp0 += acc[rt][ct][j] * ad8[ct]; }
                #pragma unroll
                for (int ct = 4; ct < 8; ++ct) { sp1 += acc[rt][ct][j] * as8[ct]; dp1 += acc[rt][ct][j] * ad8[ct]; }
                #pragma unroll
                for (int off = 1; off < 16; off <<= 1) {
                    sp0 += __shfl_xor(sp0, off); sp1 += __shfl_xor(sp1, off);
                    dp0 += __shfl_xor(dp0, off); dp1 += __shfl_xor(dp1, off);
                }
                if (l15 == 0 && row < nrows) {
                    als[(size_t)row * 2]     = sp0; als[(size_t)row * 2 + 1] = sp1;
                    ald[(size_t)row * 2]     = dp0; ald[(size_t)row * 2 + 1] = dp1;
                }
            } else {
                float sp = 0.f, dp = 0.f;
                #pragma unroll
                for (int ct = 0; ct < 8; ++ct) { sp += acc[rt][ct][j] * as8[ct]; dp += acc[rt][ct][j] * ad8[ct]; }
                #pragma unroll
                for (int off = 1; off < 16; off <<= 1) {
                    sp += __shfl_xor(sp, off); dp += __shfl_xor(dp, off);
                }
                if (l15 == 0 && row < nrows) { als[row] = sp; ald[row] = dp; }
            }
        }
    }
}

// ---- fused softmax+gather: lane-parallel softmax, LDS-broadcast gather ----
// BSPLIT=1: write bf16 (h,l) split output (layer-2 gemm input); else f32 out.
template <int H, int DO_ELU, int BSPLIT>
__global__ __launch_bounds__(256) void aggregate_kernel(const unsigned short* __restrict__ Hb,
                                                        const float* __restrict__ als,
                                                        const float* __restrict__ aldv,
                                                        const int* __restrict__ ptr,
                                                        const int* __restrict__ csr,
                                                        const float* __restrict__ bias,
                                                        float* __restrict__ out,
                                                        unsigned short* __restrict__ oh,
                                                        unsigned short* __restrict__ ol) {
    __shared__ int   s_src[4][64];
    __shared__ float s_p[4][H][64];
    const int w = threadIdx.x >> 6;
    const int lane = threadIdx.x & 63;
    const int d = blockIdx.x * 4 + w;
    if (d >= N_NODES) return;
    const int head = (H == 2) ? (lane >> 5) : 0;

    int beg = ptr[d], end = ptr[d + 1];

    float ald0, ald1 = 0.f, es0, es1 = 0.f;
    if (H == 2) {
        float2 ta = *(const float2*)(aldv + (size_t)d * 2);
        float2 ts = *(const float2*)(als + (size_t)d * 2);
        ald0 = ta.x; ald1 = ta.y;
        es0 = lrelu(ts.x + ald0); es1 = lrelu(ts.y + ald1);
    } else {
        ald0 = aldv[d]; es0 = lrelu(als[d] + ald0);
    }

    int k0 = beg + lane;
    int src0 = 0;
    float e0 = -INFINITY, e1 = -INFINITY;
    if (k0 < end) {
        src0 = csr[k0];
        if (H == 2) {
            float2 t = *(const float2*)(als + (size_t)src0 * 2);
            e0 = lrelu(t.x + ald0); e1 = lrelu(t.y + ald1);
        } else e0 = lrelu(als[src0] + ald0);
    }
    float m0 = fmaxf(es0, e0);
    float m1 = (H == 2) ? fmaxf(es1, e1) : 0.f;
    for (int k = k0 + 64; k < end; k += 64) {
        int s = csr[k];
        if (H == 2) {
            float2 t = *(const float2*)(als + (size_t)s * 2);
            m0 = fmaxf(m0, lrelu(t.x + ald0));
            m1 = fmaxf(m1, lrelu(t.y + ald1));
        } else m0 = fmaxf(m0, lrelu(als[s] + ald0));
    }
    #pragma unroll
    for (int off = 32; off; off >>= 1) {
        m0 = fmaxf(m0, __shfl_xor(m0, off));
        if (H == 2) m1 = fmaxf(m1, __shfl_xor(m1, off));
    }

    float l0 = 0.f, l1 = 0.f;
    float ax0 = 0.f, ay0 = 0.f, ax1 = 0.f, ay1 = 0.f;
    float ax2 = 0.f, ay2 = 0.f, ax3 = 0.f, ay3 = 0.f;

    for (int t0 = beg; t0 < end; t0 += 64) {
        int cnt = min(64, end - t0);
        int k = t0 + lane;
        if (k < end) {
            int s; float f0, f1 = 0.f;
            if (t0 == beg) { s = src0; f0 = e0; f1 = e1; }
            else {
                s = csr[k];
                if (H == 2) {
                    float2 t = *(const float2*)(als + (size_t)s * 2);
                    f0 = lrelu(t.x + ald0); f1 = lrelu(t.y + ald1);
                } else f0 = lrelu(als[s] + ald0);
            }
            float p0 = __expf(f0 - m0);
            l0 += p0;
            s_src[w][lane] = s;
            s_p[w][0][lane] = p0;
            if (H == 2) {
                float p1 = __expf(f1 - m1);
                l1 += p1;
                s_p[w][1][lane] = p1;
            }
        }
        int j = 0;
        for (; j + 3 < cnt; j += 4) {
            int sA = s_src[w][j],     sB = s_src[w][j + 1];
            int sC = s_src[w][j + 2], sD = s_src[w][j + 3];
            float pA = s_p[w][head][j],     pB = s_p[w][head][j + 1];
            float pC = s_p[w][head][j + 2], pD = s_p[w][head][j + 3];
            unsigned uA = ((const unsigned*)(Hb + (size_t)sA * 128))[lane];
            unsigned uB = ((const unsigned*)(Hb + (size_t)sB * 128))[lane];
            unsigned uC = ((const unsigned*)(Hb + (size_t)sC * 128))[lane];
            unsigned uD = ((const unsigned*)(Hb + (size_t)sD * 128))[lane];
            ax0 = fmaf(pA, __uint_as_float(uA << 16), ax0);
            ay0 = fmaf(pA, __uint_as_float(uA & 0xffff0000u), ay0);
            ax1 = fmaf(pB, __uint_as_float(uB << 16), ax1);
            ay1 = fmaf(pB, __uint_as_float(uB & 0xffff0000u), ay1);
            ax2 = fmaf(pC, __uint_as_float(uC << 16), ax2);
            ay2 = fmaf(pC, __uint_as_float(uC & 0xffff0000u), ay2);
            ax3 = fmaf(pD, __uint_as_float(uD << 16), ax3);
            ay3 = fmaf(pD, __uint_as_float(uD & 0xffff0000u), ay3);
        }
        for (; j < cnt; ++j) {
            int sA = s_src[w][j];
            float pA = s_p[w][head][j];
            unsigned uA = ((const unsigned*)(Hb + (size_t)sA * 128))[lane];
            ax0 = fmaf(pA, __uint_as_float(uA << 16), ax0);
            ay0 = fmaf(pA, __uint_as_float(uA & 0xffff0000u), ay0);
        }
    }

    float ax = (ax0 + ax1) + (ax2 + ax3);
    float ay = (ay0 + ay1) + (ay2 + ay3);
    float mh  = (head == 0) ? m0 : m1;
    float esh = (head == 0) ? es0 : es1;
    float psh = __expf(esh - mh);
    {
        unsigned u = ((const unsigned*)(Hb + (size_t)d * 128))[lane];
        ax = fmaf(psh, __uint_as_float(u << 16), ax);
        ay = fmaf(psh, __uint_as_float(u & 0xffff0000u), ay);
    }
    #pragma unroll
    for (int off = 32; off; off >>= 1) {
        l0 += __shfl_xor(l0, off);
        if (H == 2) l1 += __shfl_xor(l1, off);
    }
    float denom = ((head == 0) ? l0 : l1) + psh;
    float inv = 1.f / (denom + 1e-16f);
    float o0 = ax * inv + bias[2 * lane];
    float o1 = ay * inv + bias[2 * lane + 1];
    if (DO_ELU) {
        o0 = o0 > 0.f ? o0 : expm1f(o0);
        o1 = o1 > 0.f ? o1 : expm1f(o1);
    }
    if (BSPLIT) {
        unsigned h0 = bf16rne(o0), h1 = bf16rne(o1);
        ushort2 sh; sh.x = h0; sh.y = h1;
        ushort2 sl; sl.x = bf16rne(o0 - bf2f(h0)); sl.y = bf16rne(o1 - bf2f(h1));
        *(ushort2*)(oh + (size_t)d * 128 + 2 * lane) = sh;
        *(ushort2*)(ol + (size_t)d * 128 + 2 * lane) = sl;
    } else {
        ((float2*)(out + (size_t)d * 128))[lane] = make_float2(o0, o1);
    }
}

// ---------------- launch ----------------
extern "C" void kernel_launch(void* const* d_in, const int* in_sizes, int n_in,
                              void* d_out, int out_size, void* d_ws, size_t ws_size,
                              hipStream_t stream) {
    const float* x      = (const float*)d_in[0];
    const int*   ei     = (const int*)d_in[1];
    const float* W1     = (const float*)d_in[2];
    const float* a_src1 = (const float*)d_in[3];
    const float* a_dst1 = (const float*)d_in[4];
    const float* b1     = (const float*)d_in[5];
    const float* W2     = (const float*)d_in[6];
    const float* a_src2 = (const float*)d_in[7];
    const float* a_dst2 = (const float*)d_in[8];
    const float* b2     = (const float*)d_in[9];
    float* out = (float*)d_out;

    char* ws = (char*)d_ws;
    size_t off = 0;
    auto alloc = [&](size_t bytes) { void* p = ws + off; off += (bytes + 255) & ~(size_t)255; return p; };
    int*   ptr    = (int*)alloc((N_NODES + 1) * sizeof(int));
    int*   gbcnt  = (int*)alloc(NBUCK * sizeof(int));
    int*   bbase  = (int*)alloc((NBUCK + 1) * sizeof(int));
    int*   bcur   = (int*)alloc(NBUCK * sizeof(int));
    int2*  bpairs = (int2*)alloc((size_t)N_EDGES * sizeof(int2));
    int*   csr    = (int*)alloc(N_EDGES * sizeof(int));
    unsigned short* xbh = (unsigned short*)alloc((size_t)NPAD * 128 * 2);
    unsigned short* xbl = (unsigned short*)alloc((size_t)NPAD * 128 * 2);
    unsigned short* x2h = (unsigned short*)alloc((size_t)NPAD * 128 * 2);
    unsigned short* x2l = (unsigned short*)alloc((size_t)NPAD * 128 * 2);
    unsigned short* hb  = (unsigned short*)alloc((size_t)N_NODES * 128 * 2);
    unsigned short* w1h = (unsigned short*)alloc(128 * 128 * 2);
    unsigned short* w1l = (unsigned short*)alloc(128 * 128 * 2);
    unsigned short* w2h = (unsigned short*)alloc(128 * 128 * 2);
    unsigned short* w2l = (unsigned short*)alloc(128 * 128 * 2);
    float* als    = (float*)alloc(N_NODES * 2 * sizeof(float));
    float* ald    = (float*)alloc(N_NODES * 2 * sizeof(float));

    // ---- CSR build (bucket sort; same graph both layers) ----
    zerobuf_kernel<<<1, 256, 0, stream>>>(gbcnt);
    bucketcount_kernel<<<256, 256, 0, stream>>>(ei, gbcnt);
    bucketscan_kernel<<<1, 256, 0, stream>>>(gbcnt, bbase, bcur);
    bucketscatter_kernel<<<(N_EDGES + CCHUNK - 1) / CCHUNK, 256, 0, stream>>>(ei, bcur, bpairs);
    csrfinalize_kernel<<<NBUCK, 256, 0, stream>>>(bpairs, bbase, ptr, csr);

    // ---- prep: bf16 splits ----
    convx_kernel<<<(NPAD * 128 / 4 + 255) / 256, 256, 0, stream>>>(x, xbh, xbl, x2h, x2l);
    convw_kernel<<<64, 256, 0, stream>>>(W1, w1h, w1l);
    convw_kernel<<<64, 256, 0, stream>>>(W2, w2h, w2l);

    int gblocks = NPAD / 128;             // 391
    int wblocks = (N_NODES + 3) / 4;

    // ---- layer 1 ----
    gemm_mfma_kernel<2><<<gblocks, 256, 0, stream>>>(xbh, xbl, w1h, w1l, a_src1, a_dst1, hb, als, ald, N_NODES);
    aggregate_kernel<2, 1, 1><<<wblocks, 256, 0, stream>>>(hb, als, ald, ptr, csr, b1, nullptr, x2h, x2l);

    // ---- layer 2 ----
    gemm_mfma_kernel<1><<<gblocks, 256, 0, stream>>>(x2h, x2l, w2h, w2l, a_src2, a_dst2, hb, als, ald, N_NODES);
    aggregate_kernel<1, 0, 0><<<wblocks, 256, 0, stream>>>(hb, als, ald, ptr, csr, b2, out, nullptr, nullptr);
}